// Round 1
// baseline (428.628 us; speedup 1.0000x reference)
//
#include <hip/hip_runtime.h>
#include <math.h>

// Problem constants
#define B_   128
#define I_   2048
#define DIN  8
#define J_   16
#define D_   16
#define JD   256          // J_*D_ = threads per block
#define IT   16           // i's per workgroup
#define NIT  (I_/IT)      // 128 i-tiles
#define BPG  16           // b's per workgroup
#define NBG  (B_/BPG)     // 8

// ---------------------------------------------------------------------------
// Pass kernel: recompute u_hat[j,i,d] from registers (W) + LDS (x), compute
// routing logits b = sum_d vsum*u_hat, softmax over j, accumulate
// s_partial[it][b][j*16+d] = sum_{i in tile} c[b,j,i] * u_hat[b,j,i,d].
// PASS==0: c = 1/16 uniform (softmax of zeros).
// ---------------------------------------------------------------------------
template <int PASS>
__global__ __launch_bounds__(256, 2) void caps_pass(
    const float* __restrict__ x,        // [B, I, DIN]
    const float* __restrict__ W,        // [J, I, D, DIN]
    const float* __restrict__ vsum,     // [B, J, D]  (ignored when PASS==0)
    float* __restrict__ s_partial)      // [NIT, B, JD]
{
    const int it = blockIdx.x;          // i-tile index
    const int bg = blockIdx.y;          // batch-group index
    const int i0 = it * IT;
    const int b0 = bg * BPG;
    const int t  = threadIdx.x;         // 0..255
    const int j  = t >> 4;              // 0..15
    const int d  = t & 15;              // 0..15

    __shared__ float x_lds[BPG][IT][DIN];   // 8 KB
    __shared__ float bl_lds[IT][J_];        // 1 KB (logits, [i][j] for bank-free access)
    __shared__ float c_lds[IT][J_];         // 1 KB (softmax coefficients)

    // Stage x tile: 16 b x 16 i x 8 f = 2048 floats, 8 per thread.
    {
        const int bb = t >> 4, il = t & 15;
        const float4* src = reinterpret_cast<const float4*>(
            x + ((size_t)(b0 + bb) * I_ + (i0 + il)) * DIN);
        float4 a0 = src[0], a1 = src[1];
        float4* dst = reinterpret_cast<float4*>(&x_lds[bb][il][0]);
        dst[0] = a0;
        dst[1] = a1;
    }

    // Pin this thread's W slice in registers: W[j, i0+il, d, 0:8], il=0..15.
    float4 w0[IT], w1[IT];
    {
        const float* wbase = W + (((size_t)j * I_ + i0) * D_ + d) * DIN;
        #pragma unroll
        for (int il = 0; il < IT; ++il) {
            const float4* wp =
                reinterpret_cast<const float4*>(wbase + (size_t)il * D_ * DIN);
            w0[il] = wp[0];
            w1[il] = wp[1];
        }
    }
    __syncthreads();

    float u[IT];

    for (int bb = 0; bb < BPG; ++bb) {
        const int b = b0 + bb;

        // u_hat for all IT i's of this batch (8 FMAs each, operands in regs/LDS)
        #pragma unroll
        for (int il = 0; il < IT; ++il) {
            const float4* xv = reinterpret_cast<const float4*>(&x_lds[bb][il][0]);
            float4 xa = xv[0], xb = xv[1];
            u[il] = w0[il].x * xa.x + w0[il].y * xa.y + w0[il].z * xa.z +
                    w0[il].w * xa.w + w1[il].x * xb.x + w1[il].y * xb.y +
                    w1[il].z * xb.z + w1[il].w * xb.w;
        }

        float s_acc = 0.f;
        if (PASS == 0) {
            // c uniform = 1/16
            #pragma unroll
            for (int il = 0; il < IT; ++il) s_acc += u[il];
            s_acc *= (1.0f / 16.0f);
        } else {
            // Phase A: logits b[j,i] = sum_d vsum[b,j,d] * u_hat (16-lane reduce)
            const float vs = vsum[(size_t)b * JD + t];
            #pragma unroll
            for (int il = 0; il < IT; ++il) {
                float p = vs * u[il];
                p += __shfl_xor(p, 1, 16);
                p += __shfl_xor(p, 2, 16);
                p += __shfl_xor(p, 4, 16);
                p += __shfl_xor(p, 8, 16);
                if (d == 0) bl_lds[il][j] = p;
            }
            __syncthreads();

            // Phase B: softmax over j for each i. 256 threads = 16 i x 16 j.
            {
                const int il = t >> 4, jj = t & 15;
                float bl = bl_lds[il][jj];
                float mx = bl;
                mx = fmaxf(mx, __shfl_xor(mx, 1, 16));
                mx = fmaxf(mx, __shfl_xor(mx, 2, 16));
                mx = fmaxf(mx, __shfl_xor(mx, 4, 16));
                mx = fmaxf(mx, __shfl_xor(mx, 8, 16));
                float e = __expf(bl - mx);
                float sm = e;
                sm += __shfl_xor(sm, 1, 16);
                sm += __shfl_xor(sm, 2, 16);
                sm += __shfl_xor(sm, 4, 16);
                sm += __shfl_xor(sm, 8, 16);
                c_lds[il][jj] = e / sm;
            }
            __syncthreads();

            // Phase C: s accumulate (c broadcast within 16-lane group)
            #pragma unroll
            for (int il = 0; il < IT; ++il) s_acc += c_lds[il][j] * u[il];
            // No barrier needed here: next iteration's A->B barrier orders the
            // c_lds reads (here) before B's c_lds writes, and B(bb)'s bl reads
            // completed before the B->C barrier above.
        }

        s_partial[((size_t)it * B_ + b) * JD + t] = s_acc;
    }
}

// ---------------------------------------------------------------------------
// Reduce over i-tiles + squash.
// MODE 0: vout = squash(s)                (v0)
// MODE 1: vout = vA + squash(s)           (v0 + v1, logits accumulator trick)
// MODE 2: vout = squash(s)                (final output)
// ---------------------------------------------------------------------------
template <int MODE>
__global__ __launch_bounds__(256) void caps_reduce(
    const float* __restrict__ s_partial,  // [NIT, B, JD]
    const float* __restrict__ vA,         // [B, JD] (MODE==1 only)
    float* __restrict__ vout)             // [B, JD]
{
    const int b = blockIdx.x;
    const int t = threadIdx.x;

    float acc = 0.f;
    #pragma unroll 8
    for (int it = 0; it < NIT; ++it)
        acc += s_partial[((size_t)it * B_ + b) * JD + t];

    // squash: scale = sq/(1+sq)/sqrt(sq+eps), sq = sum_d s^2 per (b,j)
    float sq = acc * acc;
    sq += __shfl_xor(sq, 1, 16);
    sq += __shfl_xor(sq, 2, 16);
    sq += __shfl_xor(sq, 4, 16);
    sq += __shfl_xor(sq, 8, 16);
    const float scale = sq / (1.0f + sq) * rsqrtf(sq + 1e-7f);
    float v = scale * acc;
    if (MODE == 1) v += vA[(size_t)b * JD + t];
    vout[(size_t)b * JD + t] = v;
}

extern "C" void kernel_launch(void* const* d_in, const int* in_sizes, int n_in,
                              void* d_out, int out_size, void* d_ws,
                              size_t ws_size, hipStream_t stream) {
    const float* x = (const float*)d_in[0];   // [128, 2048, 8]
    const float* W = (const float*)d_in[1];   // [16, 2048, 16, 8]
    float* out = (float*)d_out;               // [128, 16, 16]

    // Workspace layout (floats): s_partial[NIT*B*JD] | vA[B*JD] | vB[B*JD]
    float* s_partial = (float*)d_ws;
    float* vA = s_partial + (size_t)NIT * B_ * JD;
    float* vB = vA + (size_t)B_ * JD;

    dim3 grid(NIT, NBG), blk(256);

    // r=0: c uniform -> s0 -> v0
    caps_pass<0><<<grid, blk, 0, stream>>>(x, W, nullptr, s_partial);
    caps_reduce<0><<<B_, 256, 0, stream>>>(s_partial, nullptr, vA);
    // r=1: logits = sum_d v0*u_hat -> s1 -> v1; store vB = v0 + v1
    caps_pass<1><<<grid, blk, 0, stream>>>(x, W, vA, s_partial);
    caps_reduce<1><<<B_, 256, 0, stream>>>(s_partial, vA, vB);
    // r=2: logits = sum_d (v0+v1)*u_hat -> s2 -> output v2
    caps_pass<1><<<grid, blk, 0, stream>>>(x, W, vB, s_partial);
    caps_reduce<2><<<B_, 256, 0, stream>>>(s_partial, nullptr, out);
}

// Round 2
// 242.837 us; speedup vs baseline: 1.7651x; 1.7651x over previous
//
#include <hip/hip_runtime.h>
#include <math.h>

// Problem constants
#define B_   128
#define I_   2048
#define DIN  8
#define J_   16
#define D_   16
#define JD   256          // J_*D_ = threads per block
#define IT   16           // i's per workgroup
#define NIT  (I_/IT)      // 128 i-tiles
#define BPG  16           // b's per workgroup
#define NBG  (B_/BPG)     // 8

// ---------------------------------------------------------------------------
// Pass kernel, streaming-W version (no W pinning -> no spills).
//   Phase A (PASS==1): stream W[j, i-tile, d, 0:8]; for each (il, bb) compute
//     u_hat and logit partial vs*u, 16-lane shfl reduce over d, lane d==0
//     writes logits to LDS.
//   Softmax: thread t <-> (bb, il), serial 16-j softmax in registers from LDS
//     (stride 17 -> conflict-free), writes c back in place.
//   Phase C: stream W again; s_acc[bb] += c * u_hat.
// PASS==0: uniform c = 1/16, single W stream.
// ---------------------------------------------------------------------------
template <int PASS>
__global__ __launch_bounds__(256, 4) void caps_pass(
    const float* __restrict__ x,        // [B, I, DIN]
    const float* __restrict__ W,        // [J, I, D, DIN]
    const float* __restrict__ vsum,     // [B, J, D]  (PASS==1 only)
    float* __restrict__ s_partial)      // [NIT, B, JD]
{
    const int it = blockIdx.x;          // i-tile
    const int bg = blockIdx.y;          // batch-group
    const int i0 = it * IT;
    const int b0 = bg * BPG;
    const int t  = threadIdx.x;         // 0..255
    const int j  = t >> 4;              // 0..15
    const int d  = t & 15;              // 0..15

    __shared__ float x_lds[BPG][IT][DIN];                   // 8 KB
    __shared__ float bl_lds[PASS ? BPG * IT * (J_ + 1) : 1]; // 17.4 KB (PASS=1)

    // Stage x tile: 16 b x 16 i x 8 f, 8 floats per thread, coalesced.
    {
        const int bb = t >> 4, il = t & 15;
        const float4* src = reinterpret_cast<const float4*>(
            x + ((size_t)(b0 + bb) * I_ + (i0 + il)) * DIN);
        float4 a0 = src[0], a1 = src[1];
        float4* dst = reinterpret_cast<float4*>(&x_lds[bb][il][0]);
        dst[0] = a0;
        dst[1] = a1;
    }

    const float* wbase = W + (((size_t)j * I_ + i0) * D_ + d) * DIN;

    float s_acc[BPG];
    #pragma unroll
    for (int bb = 0; bb < BPG; ++bb) s_acc[bb] = 0.f;

    if (PASS == 1) {
        float vs[BPG];
        #pragma unroll
        for (int bb = 0; bb < BPG; ++bb)
            vs[bb] = vsum[(size_t)(b0 + bb) * JD + t];
        __syncthreads();

        // ---- Phase A: logits ----
        #pragma unroll 2
        for (int il = 0; il < IT; ++il) {
            const float4* wp = reinterpret_cast<const float4*>(
                wbase + (size_t)il * D_ * DIN);
            float4 w0 = wp[0], w1 = wp[1];
            #pragma unroll
            for (int bb = 0; bb < BPG; ++bb) {
                const float4* xv =
                    reinterpret_cast<const float4*>(&x_lds[bb][il][0]);
                float4 xa = xv[0], xb = xv[1];
                float u = w0.x * xa.x + w0.y * xa.y + w0.z * xa.z +
                          w0.w * xa.w + w1.x * xb.x + w1.y * xb.y +
                          w1.z * xb.z + w1.w * xb.w;
                float p = vs[bb] * u;
                p += __shfl_xor(p, 1, 16);
                p += __shfl_xor(p, 2, 16);
                p += __shfl_xor(p, 4, 16);
                p += __shfl_xor(p, 8, 16);
                if (d == 0) bl_lds[(bb * IT + il) * (J_ + 1) + j] = p;
            }
        }
        __syncthreads();

        // ---- Softmax over j: thread t <-> (bb = t>>4, il = t&15) ----
        {
            float* row = &bl_lds[t * (J_ + 1)];
            float l[J_];
            #pragma unroll
            for (int k = 0; k < J_; ++k) l[k] = row[k];
            float mx = l[0];
            #pragma unroll
            for (int k = 1; k < J_; ++k) mx = fmaxf(mx, l[k]);
            float sum = 0.f;
            #pragma unroll
            for (int k = 0; k < J_; ++k) {
                l[k] = __expf(l[k] - mx);
                sum += l[k];
            }
            const float inv = 1.0f / sum;
            #pragma unroll
            for (int k = 0; k < J_; ++k) row[k] = l[k] * inv;
        }
        __syncthreads();

        // ---- Phase C: weighted accumulate ----
        #pragma unroll 2
        for (int il = 0; il < IT; ++il) {
            const float4* wp = reinterpret_cast<const float4*>(
                wbase + (size_t)il * D_ * DIN);
            float4 w0 = wp[0], w1 = wp[1];
            #pragma unroll
            for (int bb = 0; bb < BPG; ++bb) {
                const float4* xv =
                    reinterpret_cast<const float4*>(&x_lds[bb][il][0]);
                float4 xa = xv[0], xb = xv[1];
                float u = w0.x * xa.x + w0.y * xa.y + w0.z * xa.z +
                          w0.w * xa.w + w1.x * xb.x + w1.y * xb.y +
                          w1.z * xb.z + w1.w * xb.w;
                const float c = bl_lds[(bb * IT + il) * (J_ + 1) + j];
                s_acc[bb] += c * u;
            }
        }
    } else {
        __syncthreads();
        // ---- PASS 0: uniform c = 1/16, single W stream ----
        #pragma unroll 2
        for (int il = 0; il < IT; ++il) {
            const float4* wp = reinterpret_cast<const float4*>(
                wbase + (size_t)il * D_ * DIN);
            float4 w0 = wp[0], w1 = wp[1];
            #pragma unroll
            for (int bb = 0; bb < BPG; ++bb) {
                const float4* xv =
                    reinterpret_cast<const float4*>(&x_lds[bb][il][0]);
                float4 xa = xv[0], xb = xv[1];
                float u = w0.x * xa.x + w0.y * xa.y + w0.z * xa.z +
                          w0.w * xa.w + w1.x * xb.x + w1.y * xb.y +
                          w1.z * xb.z + w1.w * xb.w;
                s_acc[bb] += u;
            }
        }
        #pragma unroll
        for (int bb = 0; bb < BPG; ++bb) s_acc[bb] *= (1.0f / 16.0f);
    }

    #pragma unroll
    for (int bb = 0; bb < BPG; ++bb)
        s_partial[((size_t)it * B_ + (b0 + bb)) * JD + t] = s_acc[bb];
}

// ---------------------------------------------------------------------------
// Reduce over i-tiles + squash.
// MODE 0: vout = squash(s)        (v0)
// MODE 1: vout = vA + squash(s)   (v0 + v1, logits-linearity trick)
// MODE 2: vout = squash(s)        (final output)
// ---------------------------------------------------------------------------
template <int MODE>
__global__ __launch_bounds__(256) void caps_reduce(
    const float* __restrict__ s_partial,  // [NIT, B, JD]
    const float* __restrict__ vA,         // [B, JD] (MODE==1 only)
    float* __restrict__ vout)             // [B, JD]
{
    const int b = blockIdx.x;
    const int t = threadIdx.x;

    float acc = 0.f;
    #pragma unroll 8
    for (int it = 0; it < NIT; ++it)
        acc += s_partial[((size_t)it * B_ + b) * JD + t];

    float sq = acc * acc;
    sq += __shfl_xor(sq, 1, 16);
    sq += __shfl_xor(sq, 2, 16);
    sq += __shfl_xor(sq, 4, 16);
    sq += __shfl_xor(sq, 8, 16);
    const float scale = sq / (1.0f + sq) * rsqrtf(sq + 1e-7f);
    float v = scale * acc;
    if (MODE == 1) v += vA[(size_t)b * JD + t];
    vout[(size_t)b * JD + t] = v;
}

extern "C" void kernel_launch(void* const* d_in, const int* in_sizes, int n_in,
                              void* d_out, int out_size, void* d_ws,
                              size_t ws_size, hipStream_t stream) {
    const float* x = (const float*)d_in[0];   // [128, 2048, 8]
    const float* W = (const float*)d_in[1];   // [16, 2048, 16, 8]
    float* out = (float*)d_out;               // [128, 16, 16]

    // Workspace (floats): s_partial[NIT*B*JD] | vA[B*JD] | vB[B*JD]
    float* s_partial = (float*)d_ws;
    float* vA = s_partial + (size_t)NIT * B_ * JD;
    float* vB = vA + (size_t)B_ * JD;

    dim3 grid(NIT, NBG), blk(256);

    // r=0: uniform c -> s0 -> v0
    caps_pass<0><<<grid, blk, 0, stream>>>(x, W, nullptr, s_partial);
    caps_reduce<0><<<B_, 256, 0, stream>>>(s_partial, nullptr, vA);
    // r=1: logits = v0·u_hat -> s1 -> vB = v0 + v1
    caps_pass<1><<<grid, blk, 0, stream>>>(x, W, vA, s_partial);
    caps_reduce<1><<<B_, 256, 0, stream>>>(s_partial, vA, vB);
    // r=2: logits = (v0+v1)·u_hat -> s2 -> output v2
    caps_pass<1><<<grid, blk, 0, stream>>>(x, W, vB, s_partial);
    caps_reduce<2><<<B_, 256, 0, stream>>>(s_partial, nullptr, out);
}